// Round 12
// baseline (235.053 us; speedup 1.0000x reference)
//
#include <hip/hip_runtime.h>
#include <cstdint>

typedef unsigned short u16;
typedef unsigned int   u32;

#define DIM     128
#define TPITCH  136          // LDS W row pitch in bf16 (bank-spread)
#define BSH     8            // nodes per coarse bucket = 256
#define BSIZE   256
#define NBK_MAX 512          // supports n <= 131072 at BSIZE=256
#define CHUNK   4096         // edges per L1 sort block
#define FBS     128          // nodes per fused-aggregate block (half bucket)
#define CAP     2560         // LDS edge capacity (mean 2048, sd ~45, +11 sigma)

__device__ __forceinline__ u16 f2bf(float x) {   // fp32 -> bf16 RTNE
    u32 u = __float_as_uint(x);
    u32 r = u + 0x7FFFu + ((u >> 16) & 1u);
    return (u16)(r >> 16);
}

typedef __attribute__((ext_vector_type(8))) short bfrag;
typedef __attribute__((ext_vector_type(4))) float f32x4;
typedef __attribute__((ext_vector_type(2))) float f32x2;

// ---------------------------------------------------------------------------
// K1 (fat): blocks [0, nCntBlk) accumulate the global 391-bucket histogram
// (LDS-staged, atomicAdd into tot); the rest compute T(bf16) = A @ W^T with
// MFMA, restaging the C-tile through LDS for coalesced dwordx4 Tb writes.
// ---------------------------------------------------------------------------
__global__ __launch_bounds__(256) void k_count_transform(
    const float* __restrict__ A, const float* __restrict__ W,
    u16* __restrict__ Tb,
    const int* __restrict__ dst, int* __restrict__ tot,
    int n, int E, int nCntBlk, int NBK)
{
    __shared__ u16 Wb[DIM * TPITCH];   // 34816 B; count blocks reuse as hist

    if (blockIdx.x < nCntBlk) {
        int* hist = (int*)Wb;
        for (int i = threadIdx.x; i < NBK; i += 256) hist[i] = 0;
        __syncthreads();
        const int base = blockIdx.x * CHUNK;
        const int end  = min(base + CHUNK, E);
        for (int i = base + threadIdx.x; i < end; i += 256)
            atomicAdd(&hist[dst[i] >> BSH], 1);
        __syncthreads();
        for (int b = threadIdx.x; b < NBK; b += 256) {
            const int h = hist[b];
            if (h) atomicAdd(&tot[b], h);
        }
        return;
    }

    // stage W as bf16: Wb[j][k] = bf16(W[j][k]); thread t -> row t>>1, half (t&1)*64
    {
        const int j  = threadIdx.x >> 1;
        const int k0 = (threadIdx.x & 1) << 6;
        const float* wr = W + j * DIM + k0;
        u16* wo = Wb + j * TPITCH + k0;
#pragma unroll
        for (int k = 0; k < 64; k += 4) {
            float4 v = *(const float4*)(wr + k);
            ushort4 h;
            h.x = f2bf(v.x); h.y = f2bf(v.y); h.z = f2bf(v.z); h.w = f2bf(v.w);
            *(ushort4*)(wo + k) = h;
        }
    }
    __syncthreads();

    const int wave = threadIdx.x >> 6;
    const int lane = threadIdx.x & 63;
    const int quad = lane >> 4;
    const int l16  = lane & 15;

    const int r0b = (blockIdx.x - nCntBlk) << 6;          // block's first row
    const int r0  = r0b + (wave << 4);                    // wave's first row
    const bool active = (r0 < n);                         // predicate, no return

    f32x4 acc[8];
#pragma unroll
    for (int c = 0; c < 8; ++c) acc[c] = (f32x4)(0.f);

    if (active) {
        const int ar = min(r0 + l16, n - 1);   // A-frag row (clamped on tail)
        const float* arow = A + (size_t)ar * DIM;
#pragma unroll
        for (int s = 0; s < 4; ++s) {
            const int koff = (s << 5) + (quad << 3);
            const float4 f0 = *(const float4*)(arow + koff);
            const float4 f1 = *(const float4*)(arow + koff + 4);
            bfrag a;
            a[0] = (short)f2bf(f0.x); a[1] = (short)f2bf(f0.y);
            a[2] = (short)f2bf(f0.z); a[3] = (short)f2bf(f0.w);
            a[4] = (short)f2bf(f1.x); a[5] = (short)f2bf(f1.y);
            a[6] = (short)f2bf(f1.z); a[7] = (short)f2bf(f1.w);
#pragma unroll
            for (int c = 0; c < 8; ++c) {
                const int nn = (c << 4) + l16;     // B col; B[k][n] = W[n][k]
                const bfrag b = *(const bfrag*)(Wb + nn * TPITCH + koff);
                acc[c] = __builtin_amdgcn_mfma_f32_16x16x32_bf16(a, b, acc[c], 0, 0, 0);
            }
        }
    }

    __syncthreads();                 // all Wb reads complete; reuse as C-tile

    // restage C: tile[row_local][col], pitch TPITCH (bank-spread)
    if (active) {
        const int rl0 = (wave << 4) + (quad << 2);
#pragma unroll
        for (int r = 0; r < 4; ++r) {
            u16* trow = Wb + (rl0 + r) * TPITCH + l16;
#pragma unroll
            for (int c = 0; c < 8; ++c)
                trow[c << 4] = f2bf(acc[c][r]);
        }
    }
    __syncthreads();

    // coalesced flush: thread t -> row t>>2, 64B chunk t&3 (4 x dwordx4)
    {
        const int rl  = threadIdx.x >> 2;
        const int row = r0b + rl;
        if (row < n) {
            const float4* sp = (const float4*)(Wb + rl * TPITCH + ((threadIdx.x & 3) << 5));
            float4* dp = (float4*)(Tb + (size_t)row * DIM + ((threadIdx.x & 3) << 5));
            dp[0] = sp[0];
            dp[1] = sp[1];
            dp[2] = sp[2];
            dp[3] = sp[3];
        }
    }
}

// ---------------------------------------------------------------------------
// K2: single-block exclusive scan of tot[NBK] -> bucketStart[NBK+1];
// also initializes cursor[] = bucketStart[] (run-claim cursors for K3).
// NBK <= 512.
// ---------------------------------------------------------------------------
__global__ __launch_bounds__(512) void k_scan(
    const int* __restrict__ tot, int* __restrict__ bucketStart,
    int* __restrict__ cursor, int NBK, int E)
{
    __shared__ int sc[512];
    const int t = threadIdx.x;
    const int v = (t < NBK) ? tot[t] : 0;
    sc[t] = v; __syncthreads();
    for (int d = 1; d < 512; d <<= 1) {
        int u = (t >= d) ? sc[t - d] : 0;
        __syncthreads();
        sc[t] += u;
        __syncthreads();
    }
    if (t < NBK) {
        const int excl = sc[t] - v;
        bucketStart[t] = excl;
        cursor[t] = excl;
    }
    if (t == 0) bucketStart[NBK] = E;
}

// ---------------------------------------------------------------------------
// K3: L1 scatter, LDS-staged, atomic run-claim (no cnt matrix). Each block
// histograms its CHUNK edges, scans in LDS, claims per-bucket output runs
// via atomicAdd(cursor[b], len) (within-bucket order irrelevant downstream),
// bucket-sorts the chunk in LDS, flushes with coalesced contiguous writes
// (avg run 4096/391 = 10.5 edges = 84 B).
// Payload: x = src | (dst&255)<<20, y = w bits.
// ---------------------------------------------------------------------------
__global__ __launch_bounds__(512) void k_scatter(
    const int* __restrict__ src, const int* __restrict__ dst,
    const float* __restrict__ w, int* __restrict__ cursor,
    int2* __restrict__ es1, int E, int NBK)
{
    __shared__ int2 buf[CHUNK];          // 32 KB staged payload
    __shared__ u16  bid[CHUNK];          // bucket id per slot (8 KB)
    __shared__ int  hist[NBK_MAX];       // 2 KB
    __shared__ int  gbase[NBK_MAX];      // global run base for this block
    __shared__ int  lbase[NBK_MAX];      // local run base in buf
    __shared__ int  lpos[NBK_MAX];       // running local position
    __shared__ int  sc[512];             // scan scratch

    const int blk  = blockIdx.x;
    const int base = blk * CHUNK;
    const int end  = min(base + CHUNK, E);
    const int len  = end - base;
    const int t    = threadIdx.x;

    if (t < NBK) hist[t] = 0;
    __syncthreads();
    for (int i = base + t; i < end; i += 512)
        atomicAdd(&hist[dst[i] >> BSH], 1);
    __syncthreads();

    // exclusive scan of hist -> lbase/lpos; claim global runs
    const int v = (t < NBK) ? hist[t] : 0;
    sc[t] = v;
    __syncthreads();
    for (int d = 1; d < 512; d <<= 1) {
        int u = (t >= d) ? sc[t - d] : 0;
        __syncthreads();
        sc[t] += u;
        __syncthreads();
    }
    if (t < NBK) {
        const int ex = sc[t] - v;
        lbase[t] = ex;
        lpos[t]  = ex;
        if (v) gbase[t] = atomicAdd(&cursor[t], v);
    }
    __syncthreads();

    // scatter into LDS (scattered 8B writes stay on-chip)
    for (int i = base + t; i < end; i += 512) {
        const int d   = dst[i];
        const int bkt = d >> BSH;
        const int p   = atomicAdd(&lpos[bkt], 1);
        buf[p] = make_int2(src[i] | ((d & (BSIZE - 1)) << 20),
                           __float_as_int(w[i]));
        bid[p] = (u16)bkt;
    }
    __syncthreads();

    // coalesced flush: consecutive i -> consecutive global addresses per run
    for (int i = t; i < len; i += 512) {
        const int bkt = bid[i];
        es1[gbase[bkt] + (i - lbase[bkt])] = buf[i];
    }
}

// ---------------------------------------------------------------------------
// K5 (fused fine-sort + aggregate): one block per 128-node half-bucket,
// 512 threads (8 waves). Filter on dlocal high bit, 20 KB LDS CSR sort,
// then the measured-best unroll-8 per-node loop. (r10/r11 form, unchanged.)
// ---------------------------------------------------------------------------
__global__ __launch_bounds__(512) void gnn_aggregate(
    const u16* __restrict__ Tb, const int* __restrict__ bucketStart,
    const int2* __restrict__ es1, float* __restrict__ out, int n)
{
    __shared__ int2 buf[CAP];           // 20 KB sorted edges
    __shared__ int  cnt[FBS];
    __shared__ int  loff[FBS + 1];
    __shared__ int  cur[FBS];
    __shared__ int  sc[FBS];

    const int f    = blockIdx.x;
    const int c    = f >> 1;            // parent coarse bucket
    const int hbit = (f & 1) << 7;      // half selector on dlocal bit 7
    const int s    = bucketStart[c], e = bucketStart[c + 1];
    const int v0   = f << 7;            // first node id of this block
    const int t    = threadIdx.x;
    const int lane = t & 63;
    const int wv   = t >> 6;            // 0..7
    const u32* Tw  = (const u32*)Tb;

    if (t < FBS) cnt[t] = 0;
    __syncthreads();
    for (int i = s + t; i < e; i += 512) {
        const int d8 = (es1[i].x >> 20) & 255;
        if ((d8 & 128) == hbit) atomicAdd(&cnt[d8 & 127], 1);
    }
    __syncthreads();

    int myc = 0;
    if (t < FBS) { myc = cnt[t]; sc[t] = myc; }
    __syncthreads();
    for (int d = 1; d < FBS; d <<= 1) {
        int u = 0;
        if (t < FBS && t >= d) u = sc[t - d];
        __syncthreads();
        if (t < FBS) sc[t] += u;
        __syncthreads();
    }
    if (t < FBS) {
        const int ex = sc[t] - myc;
        loff[t] = ex; cur[t] = ex;
        if (t == FBS - 1) loff[FBS] = sc[t];   // == kept edge count
    }
    __syncthreads();
    const int kept = loff[FBS];

    if (kept <= CAP) {
        for (int i = s + t; i < e; i += 512) {
            const int2 ev = es1[i];
            const int d8 = (ev.x >> 20) & 255;
            if ((d8 & 128) == hbit) {
                const int p = atomicAdd(&cur[d8 & 127], 1);
                buf[p] = make_int2(ev.x & 0xFFFFF, ev.y);
            }
        }
        __syncthreads();

        // phase B: wave wv owns local nodes [wv*16, wv*16+16)
        for (int nt = 0; nt < 16; ++nt) {
            const int tn = (wv << 4) + nt;
            const int v  = v0 + tn;
            if (v >= n) break;                    // wave-uniform
            const int kb = loff[tn], ke = loff[tn + 1];
            float ax0 = 0.f, ay0 = 0.f, ax1 = 0.f, ay1 = 0.f;

            int i = kb;
            for (; i + 7 < ke; i += 8) {
                const int2 e0 = buf[i],     e1 = buf[i + 1], e2 = buf[i + 2], e3 = buf[i + 3];
                const int2 e4 = buf[i + 4], e5 = buf[i + 5], e6 = buf[i + 6], e7 = buf[i + 7];
                const u32 t0 = Tw[(size_t)e0.x * 64 + lane];
                const u32 t1 = Tw[(size_t)e1.x * 64 + lane];
                const u32 t2 = Tw[(size_t)e2.x * 64 + lane];
                const u32 t3 = Tw[(size_t)e3.x * 64 + lane];
                const u32 t4 = Tw[(size_t)e4.x * 64 + lane];
                const u32 t5 = Tw[(size_t)e5.x * 64 + lane];
                const u32 t6 = Tw[(size_t)e6.x * 64 + lane];
                const u32 t7 = Tw[(size_t)e7.x * 64 + lane];
                const float w0 = __int_as_float(e0.y), w1 = __int_as_float(e1.y);
                const float w2 = __int_as_float(e2.y), w3 = __int_as_float(e3.y);
                const float w4 = __int_as_float(e4.y), w5 = __int_as_float(e5.y);
                const float w6 = __int_as_float(e6.y), w7 = __int_as_float(e7.y);
                ax0 += w0 * __uint_as_float(t0 << 16);
                ay0 += w0 * __uint_as_float(t0 & 0xFFFF0000u);
                ax1 += w1 * __uint_as_float(t1 << 16);
                ay1 += w1 * __uint_as_float(t1 & 0xFFFF0000u);
                ax0 += w2 * __uint_as_float(t2 << 16);
                ay0 += w2 * __uint_as_float(t2 & 0xFFFF0000u);
                ax1 += w3 * __uint_as_float(t3 << 16);
                ay1 += w3 * __uint_as_float(t3 & 0xFFFF0000u);
                ax0 += w4 * __uint_as_float(t4 << 16);
                ay0 += w4 * __uint_as_float(t4 & 0xFFFF0000u);
                ax1 += w5 * __uint_as_float(t5 << 16);
                ay1 += w5 * __uint_as_float(t5 & 0xFFFF0000u);
                ax0 += w6 * __uint_as_float(t6 << 16);
                ay0 += w6 * __uint_as_float(t6 & 0xFFFF0000u);
                ax1 += w7 * __uint_as_float(t7 << 16);
                ay1 += w7 * __uint_as_float(t7 & 0xFFFF0000u);
            }
            for (; i + 3 < ke; i += 4) {
                const int2 e0 = buf[i], e1 = buf[i + 1], e2 = buf[i + 2], e3 = buf[i + 3];
                const u32 t0 = Tw[(size_t)e0.x * 64 + lane];
                const u32 t1 = Tw[(size_t)e1.x * 64 + lane];
                const u32 t2 = Tw[(size_t)e2.x * 64 + lane];
                const u32 t3 = Tw[(size_t)e3.x * 64 + lane];
                const float w0 = __int_as_float(e0.y), w1 = __int_as_float(e1.y);
                const float w2 = __int_as_float(e2.y), w3 = __int_as_float(e3.y);
                ax0 += w0 * __uint_as_float(t0 << 16);
                ay0 += w0 * __uint_as_float(t0 & 0xFFFF0000u);
                ax1 += w1 * __uint_as_float(t1 << 16);
                ay1 += w1 * __uint_as_float(t1 & 0xFFFF0000u);
                ax0 += w2 * __uint_as_float(t2 << 16);
                ay0 += w2 * __uint_as_float(t2 & 0xFFFF0000u);
                ax1 += w3 * __uint_as_float(t3 << 16);
                ay1 += w3 * __uint_as_float(t3 & 0xFFFF0000u);
            }
            for (; i < ke; ++i) {
                const int2 ev = buf[i];
                const u32 tv = Tw[(size_t)ev.x * 64 + lane];
                const float w0 = __int_as_float(ev.y);
                ax0 += w0 * __uint_as_float(tv << 16);
                ay0 += w0 * __uint_as_float(tv & 0xFFFF0000u);
            }

            f32x2 r;
            r[0] = ax0 + ax1;
            r[1] = ay0 + ay1;
            __builtin_nontemporal_store(r, (f32x2*)(out + (size_t)v * DIM + 2 * lane));
        }
    } else {
        // slow-correct fallback: filter-scan the coarse window per node
        for (int nt = 0; nt < 16; ++nt) {
            const int tn = (wv << 4) + nt;
            const int v  = v0 + tn;
            if (v >= n) break;
            const int want = hbit | tn;
            float ax = 0.f, ay = 0.f;
            for (int i = s; i < e; ++i) {
                const int2 ev = es1[i];
                if (((ev.x >> 20) & 255) == want) {
                    const u32 tv = Tw[(size_t)(ev.x & 0xFFFFF) * 64 + lane];
                    const float wgt = __int_as_float(ev.y);
                    ax += wgt * __uint_as_float(tv << 16);
                    ay += wgt * __uint_as_float(tv & 0xFFFF0000u);
                }
            }
            f32x2 r; r[0] = ax; r[1] = ay;
            __builtin_nontemporal_store(r, (f32x2*)(out + (size_t)v * DIM + 2 * lane));
        }
    }
}

// ---------------------------------------------------------------------------
extern "C" void kernel_launch(void* const* d_in, const int* in_sizes, int n_in,
                              void* d_out, int out_size, void* d_ws, size_t ws_size,
                              hipStream_t stream)
{
    const float* node_emb = (const float*)d_in[0];
    const float* ew       = (const float*)d_in[1];
    const int*   src      = (const int*)d_in[2];
    const int*   dst      = (const int*)d_in[3];
    const float* W        = (const float*)d_in[4];
    float* out = (float*)d_out;

    const int n = in_sizes[0] / DIM;            // 100000
    const int E = in_sizes[1];                  // 1600000
    const int NBK = (n + BSIZE - 1) >> BSH;     // 391 coarse buckets
    const int nCntBlk = (E + CHUNK - 1) / CHUNK;// 391 L1 blocks
    const int nfine = (n + FBS - 1) / FBS;      // 782 aggregate blocks

    // workspace layout (256B-aligned chunks)
    char* ws = (char*)d_ws;
    size_t o = 0;
    u16* Tb = (u16*)(ws + o);  o += (((size_t)n * DIM * sizeof(u16)) + 255) & ~255ULL;
    int* tot = (int*)(ws + o); o += (((size_t)NBK * sizeof(int)) + 255) & ~255ULL;
    int* bucketStart = (int*)(ws + o); o += (((size_t)(NBK + 1) * sizeof(int)) + 255) & ~255ULL;
    int* cursor = (int*)(ws + o); o += (((size_t)NBK * sizeof(int)) + 255) & ~255ULL;
    int2* es1 = (int2*)(ws + o);

    const int ntiles = (n + 63) >> 6;           // 64 rows per transform block

    // zero the global histogram (tiny, capture-safe)
    hipMemsetAsync(tot, 0, (size_t)NBK * sizeof(int), stream);

    // K1: fused bucket-count + MFMA transform (coalesced Tb write via restage)
    k_count_transform<<<nCntBlk + ntiles, 256, 0, stream>>>(
        node_emb, W, Tb, dst, tot, n, E, nCntBlk, NBK);

    // K2: single-block scan -> bucketStart + cursor init
    k_scan<<<1, 512, 0, stream>>>(tot, bucketStart, cursor, NBK, E);

    // K3: LDS-staged scatter with atomic run-claim, coalesced flush
    k_scatter<<<nCntBlk, 512, 0, stream>>>(src, dst, ew, cursor, es1, E, NBK);

    // K5: fused filter + fine-sort + aggregate (512 threads, 8 waves/block)
    gnn_aggregate<<<nfine, 512, 0, stream>>>(Tb, bucketStart, es1, out, n);
}

// Round 13
// 232.408 us; speedup vs baseline: 1.0114x; 1.0114x over previous
//
#include <hip/hip_runtime.h>
#include <cstdint>

typedef unsigned short u16;
typedef unsigned int   u32;

#define DIM     128
#define TPITCH  136          // LDS W row pitch in bf16 (bank-spread)
#define BSH     8            // nodes per coarse bucket = 256
#define BSIZE   256
#define NBK_MAX 512          // supports n <= 131072 at BSIZE=256
#define CHUNK   4096         // edges per L1 sort block
#define FBS     128          // nodes per fused-aggregate block (half bucket)
#define CAP     2560         // LDS edge capacity (mean 2048, sd ~45, +11 sigma)

__device__ __forceinline__ u16 f2bf(float x) {   // fp32 -> bf16 RTNE
    u32 u = __float_as_uint(x);
    u32 r = u + 0x7FFFu + ((u >> 16) & 1u);
    return (u16)(r >> 16);
}

typedef __attribute__((ext_vector_type(8))) short bfrag;
typedef __attribute__((ext_vector_type(4))) float f32x4;
typedef __attribute__((ext_vector_type(2))) float f32x2;

// ---------------------------------------------------------------------------
// K1 (fat): blocks [0, nCntBlk) do the L1 bucket count, writing their cnt
// column AND accumulating tot[b] via global atomics (replaces k_rowsum);
// the rest compute T(bf16) = A @ W^T with MFMA, restaging the C-tile
// through LDS for coalesced dwordx4 Tb writes.
// ---------------------------------------------------------------------------
__global__ __launch_bounds__(256) void k_count_transform(
    const float* __restrict__ A, const float* __restrict__ W,
    u16* __restrict__ Tb,
    const int* __restrict__ dst, int* __restrict__ cnt, int* __restrict__ tot,
    int n, int E, int nCntBlk, int NBK)
{
    __shared__ u16 Wb[DIM * TPITCH];   // 34816 B; count blocks reuse as hist

    if (blockIdx.x < nCntBlk) {
        int* hist = (int*)Wb;
        for (int i = threadIdx.x; i < NBK; i += 256) hist[i] = 0;
        __syncthreads();
        const int base = blockIdx.x * CHUNK;
        const int end  = min(base + CHUNK, E);
        for (int i = base + threadIdx.x; i < end; i += 256)
            atomicAdd(&hist[dst[i] >> BSH], 1);
        __syncthreads();
        for (int b = threadIdx.x; b < NBK; b += 256) {
            const int h = hist[b];
            cnt[b * nCntBlk + blockIdx.x] = h;
            if (h) atomicAdd(&tot[b], h);        // fused rowsum
        }
        return;
    }

    // stage W as bf16: Wb[j][k] = bf16(W[j][k]); thread t -> row t>>1, half (t&1)*64
    {
        const int j  = threadIdx.x >> 1;
        const int k0 = (threadIdx.x & 1) << 6;
        const float* wr = W + j * DIM + k0;
        u16* wo = Wb + j * TPITCH + k0;
#pragma unroll
        for (int k = 0; k < 64; k += 4) {
            float4 v = *(const float4*)(wr + k);
            ushort4 h;
            h.x = f2bf(v.x); h.y = f2bf(v.y); h.z = f2bf(v.z); h.w = f2bf(v.w);
            *(ushort4*)(wo + k) = h;
        }
    }
    __syncthreads();

    const int wave = threadIdx.x >> 6;
    const int lane = threadIdx.x & 63;
    const int quad = lane >> 4;
    const int l16  = lane & 15;

    const int r0b = (blockIdx.x - nCntBlk) << 6;          // block's first row
    const int r0  = r0b + (wave << 4);                    // wave's first row
    const bool active = (r0 < n);                         // predicate, no return

    f32x4 acc[8];
#pragma unroll
    for (int c = 0; c < 8; ++c) acc[c] = (f32x4)(0.f);

    if (active) {
        const int ar = min(r0 + l16, n - 1);   // A-frag row (clamped on tail)
        const float* arow = A + (size_t)ar * DIM;
#pragma unroll
        for (int s = 0; s < 4; ++s) {
            const int koff = (s << 5) + (quad << 3);
            const float4 f0 = *(const float4*)(arow + koff);
            const float4 f1 = *(const float4*)(arow + koff + 4);
            bfrag a;
            a[0] = (short)f2bf(f0.x); a[1] = (short)f2bf(f0.y);
            a[2] = (short)f2bf(f0.z); a[3] = (short)f2bf(f0.w);
            a[4] = (short)f2bf(f1.x); a[5] = (short)f2bf(f1.y);
            a[6] = (short)f2bf(f1.z); a[7] = (short)f2bf(f1.w);
#pragma unroll
            for (int c = 0; c < 8; ++c) {
                const int nn = (c << 4) + l16;     // B col; B[k][n] = W[n][k]
                const bfrag b = *(const bfrag*)(Wb + nn * TPITCH + koff);
                acc[c] = __builtin_amdgcn_mfma_f32_16x16x32_bf16(a, b, acc[c], 0, 0, 0);
            }
        }
    }

    __syncthreads();                 // all Wb reads complete; reuse as C-tile

    // restage C: tile[row_local][col], pitch TPITCH (bank-spread)
    if (active) {
        const int rl0 = (wave << 4) + (quad << 2);
#pragma unroll
        for (int r = 0; r < 4; ++r) {
            u16* trow = Wb + (rl0 + r) * TPITCH + l16;
#pragma unroll
            for (int c = 0; c < 8; ++c)
                trow[c << 4] = f2bf(acc[c][r]);
        }
    }
    __syncthreads();

    // coalesced flush: thread t -> row t>>2, 64B chunk t&3 (4 x dwordx4)
    {
        const int rl  = threadIdx.x >> 2;
        const int row = r0b + rl;
        if (row < n) {
            const float4* sp = (const float4*)(Wb + rl * TPITCH + ((threadIdx.x & 3) << 5));
            float4* dp = (float4*)(Tb + (size_t)row * DIM + ((threadIdx.x & 3) << 5));
            dp[0] = sp[0];
            dp[1] = sp[1];
            dp[2] = sp[2];
            dp[3] = sp[3];
        }
    }
}

// ---------------------------------------------------------------------------
// K2bc (fused): every block recomputes bucketStart = exscan(tot) in LDS;
// block 0 publishes it; each block then scans its cnt row offset by its base.
// ---------------------------------------------------------------------------
__global__ __launch_bounds__(512) void k_scan_all(
    const int* __restrict__ tot, int* __restrict__ bucketStart,
    int* __restrict__ cnt, int NBK, int nCntBlk, int E)
{
    __shared__ int sc[512];
    __shared__ int bs;                    // this block's bucket base
    const int t = threadIdx.x;
    const int b = blockIdx.x;

    // pass 1: scan tot
    const int v = (t < NBK) ? tot[t] : 0;
    sc[t] = v; __syncthreads();
    for (int d = 1; d < 512; d <<= 1) {
        int u = (t >= d) ? sc[t - d] : 0;
        __syncthreads();
        sc[t] += u;
        __syncthreads();
    }
    if (t == b) bs = sc[t] - v;           // exclusive prefix at b (b < 512)
    if (b == 0) {
        if (t < NBK) bucketStart[t] = sc[t] - v;
        if (t == 0)  bucketStart[NBK] = E;
    }
    __syncthreads();                      // bs visible; sc reusable

    // pass 2: scan cnt row b, offset by bs
    int* row = cnt + b * nCntBlk;
    const int rv = (t < nCntBlk) ? row[t] : 0;
    sc[t] = rv; __syncthreads();
    for (int d = 1; d < 512; d <<= 1) {
        int u = (t >= d) ? sc[t - d] : 0;
        __syncthreads();
        sc[t] += u;
        __syncthreads();
    }
    if (t < nCntBlk) row[t] = bs + sc[t] - rv;
}

// ---------------------------------------------------------------------------
// K3: L1 scatter, LDS-staged. The chunk's edges are bucket-sorted into a
// 32 KB LDS buffer, then flushed with fully coalesced contiguous writes into
// the block-exclusive global runs (positions from the scanned cnt matrix).
// Payload: x = src | (dst&255)<<20, y = w bits.  (avg run 10.5 edges = 84 B)
// ---------------------------------------------------------------------------
__global__ __launch_bounds__(512) void k_scatter(
    const int* __restrict__ src, const int* __restrict__ dst,
    const float* __restrict__ w, const int* __restrict__ cnt,
    const int* __restrict__ bucketStart,
    int2* __restrict__ es1, int E, int nCntBlk, int NBK)
{
    __shared__ int2 buf[CHUNK];          // 32 KB staged payload
    __shared__ u16  bid[CHUNK];          // bucket id per slot (8 KB)
    __shared__ int  gbase[NBK_MAX];      // global run base for this block
    __shared__ int  lbase[NBK_MAX];      // local run base in buf
    __shared__ int  lpos[NBK_MAX];       // running local position
    __shared__ int  sc[512];             // scan scratch

    const int blk  = blockIdx.x;
    const int base = blk * CHUNK;
    const int end  = min(base + CHUNK, E);
    const int len  = end - base;
    const int t    = threadIdx.x;

    // run length per bucket for this block, from the scanned cnt matrix
    int mylen = 0;
    if (t < NBK) {
        const int g = cnt[t * nCntBlk + blk];
        gbase[t] = g;
        const int nxt = (blk + 1 < nCntBlk) ? cnt[t * nCntBlk + blk + 1]
                                            : bucketStart[t + 1];
        mylen = nxt - g;
    }
    sc[t] = (t < NBK) ? mylen : 0;
    __syncthreads();
    for (int d = 1; d < 512; d <<= 1) {
        int v = (t >= d) ? sc[t - d] : 0;
        __syncthreads();
        sc[t] += v;
        __syncthreads();
    }
    if (t < NBK) {
        const int ex = sc[t] - mylen;    // exclusive scan -> local base
        lbase[t] = ex;
        lpos[t]  = ex;
    }
    __syncthreads();

    // scatter into LDS (scattered 8B writes stay on-chip)
    for (int i = base + t; i < end; i += 512) {
        const int d   = dst[i];
        const int bkt = d >> BSH;
        const int p   = atomicAdd(&lpos[bkt], 1);
        buf[p] = make_int2(src[i] | ((d & (BSIZE - 1)) << 20),
                           __float_as_int(w[i]));
        bid[p] = (u16)bkt;
    }
    __syncthreads();

    // coalesced flush: consecutive i -> consecutive global addresses per run
    for (int i = t; i < len; i += 512) {
        const int bkt = bid[i];
        es1[gbase[bkt] + (i - lbase[bkt])] = buf[i];
    }
}

// ---------------------------------------------------------------------------
// K5 (fused fine-sort + aggregate): one block per 128-node half-bucket,
// 512 threads (8 waves). Filter on dlocal high bit, 20 KB LDS CSR sort,
// then the measured-best unroll-8 per-node loop. (r10/r11 form, unchanged.)
// ---------------------------------------------------------------------------
__global__ __launch_bounds__(512) void gnn_aggregate(
    const u16* __restrict__ Tb, const int* __restrict__ bucketStart,
    const int2* __restrict__ es1, float* __restrict__ out, int n)
{
    __shared__ int2 buf[CAP];           // 20 KB sorted edges
    __shared__ int  cnt[FBS];
    __shared__ int  loff[FBS + 1];
    __shared__ int  cur[FBS];
    __shared__ int  sc[FBS];

    const int f    = blockIdx.x;
    const int c    = f >> 1;            // parent coarse bucket
    const int hbit = (f & 1) << 7;      // half selector on dlocal bit 7
    const int s    = bucketStart[c], e = bucketStart[c + 1];
    const int v0   = f << 7;            // first node id of this block
    const int t    = threadIdx.x;
    const int lane = t & 63;
    const int wv   = t >> 6;            // 0..7
    const u32* Tw  = (const u32*)Tb;

    if (t < FBS) cnt[t] = 0;
    __syncthreads();
    for (int i = s + t; i < e; i += 512) {
        const int d8 = (es1[i].x >> 20) & 255;
        if ((d8 & 128) == hbit) atomicAdd(&cnt[d8 & 127], 1);
    }
    __syncthreads();

    int myc = 0;
    if (t < FBS) { myc = cnt[t]; sc[t] = myc; }
    __syncthreads();
    for (int d = 1; d < FBS; d <<= 1) {
        int u = 0;
        if (t < FBS && t >= d) u = sc[t - d];
        __syncthreads();
        if (t < FBS) sc[t] += u;
        __syncthreads();
    }
    if (t < FBS) {
        const int ex = sc[t] - myc;
        loff[t] = ex; cur[t] = ex;
        if (t == FBS - 1) loff[FBS] = sc[t];   // == kept edge count
    }
    __syncthreads();
    const int kept = loff[FBS];

    if (kept <= CAP) {
        for (int i = s + t; i < e; i += 512) {
            const int2 ev = es1[i];
            const int d8 = (ev.x >> 20) & 255;
            if ((d8 & 128) == hbit) {
                const int p = atomicAdd(&cur[d8 & 127], 1);
                buf[p] = make_int2(ev.x & 0xFFFFF, ev.y);
            }
        }
        __syncthreads();

        // phase B: wave wv owns local nodes [wv*16, wv*16+16)
        for (int nt = 0; nt < 16; ++nt) {
            const int tn = (wv << 4) + nt;
            const int v  = v0 + tn;
            if (v >= n) break;                    // wave-uniform
            const int kb = loff[tn], ke = loff[tn + 1];
            float ax0 = 0.f, ay0 = 0.f, ax1 = 0.f, ay1 = 0.f;

            int i = kb;
            for (; i + 7 < ke; i += 8) {
                const int2 e0 = buf[i],     e1 = buf[i + 1], e2 = buf[i + 2], e3 = buf[i + 3];
                const int2 e4 = buf[i + 4], e5 = buf[i + 5], e6 = buf[i + 6], e7 = buf[i + 7];
                const u32 t0 = Tw[(size_t)e0.x * 64 + lane];
                const u32 t1 = Tw[(size_t)e1.x * 64 + lane];
                const u32 t2 = Tw[(size_t)e2.x * 64 + lane];
                const u32 t3 = Tw[(size_t)e3.x * 64 + lane];
                const u32 t4 = Tw[(size_t)e4.x * 64 + lane];
                const u32 t5 = Tw[(size_t)e5.x * 64 + lane];
                const u32 t6 = Tw[(size_t)e6.x * 64 + lane];
                const u32 t7 = Tw[(size_t)e7.x * 64 + lane];
                const float w0 = __int_as_float(e0.y), w1 = __int_as_float(e1.y);
                const float w2 = __int_as_float(e2.y), w3 = __int_as_float(e3.y);
                const float w4 = __int_as_float(e4.y), w5 = __int_as_float(e5.y);
                const float w6 = __int_as_float(e6.y), w7 = __int_as_float(e7.y);
                ax0 += w0 * __uint_as_float(t0 << 16);
                ay0 += w0 * __uint_as_float(t0 & 0xFFFF0000u);
                ax1 += w1 * __uint_as_float(t1 << 16);
                ay1 += w1 * __uint_as_float(t1 & 0xFFFF0000u);
                ax0 += w2 * __uint_as_float(t2 << 16);
                ay0 += w2 * __uint_as_float(t2 & 0xFFFF0000u);
                ax1 += w3 * __uint_as_float(t3 << 16);
                ay1 += w3 * __uint_as_float(t3 & 0xFFFF0000u);
                ax0 += w4 * __uint_as_float(t4 << 16);
                ay0 += w4 * __uint_as_float(t4 & 0xFFFF0000u);
                ax1 += w5 * __uint_as_float(t5 << 16);
                ay1 += w5 * __uint_as_float(t5 & 0xFFFF0000u);
                ax0 += w6 * __uint_as_float(t6 << 16);
                ay0 += w6 * __uint_as_float(t6 & 0xFFFF0000u);
                ax1 += w7 * __uint_as_float(t7 << 16);
                ay1 += w7 * __uint_as_float(t7 & 0xFFFF0000u);
            }
            for (; i + 3 < ke; i += 4) {
                const int2 e0 = buf[i], e1 = buf[i + 1], e2 = buf[i + 2], e3 = buf[i + 3];
                const u32 t0 = Tw[(size_t)e0.x * 64 + lane];
                const u32 t1 = Tw[(size_t)e1.x * 64 + lane];
                const u32 t2 = Tw[(size_t)e2.x * 64 + lane];
                const u32 t3 = Tw[(size_t)e3.x * 64 + lane];
                const float w0 = __int_as_float(e0.y), w1 = __int_as_float(e1.y);
                const float w2 = __int_as_float(e2.y), w3 = __int_as_float(e3.y);
                ax0 += w0 * __uint_as_float(t0 << 16);
                ay0 += w0 * __uint_as_float(t0 & 0xFFFF0000u);
                ax1 += w1 * __uint_as_float(t1 << 16);
                ay1 += w1 * __uint_as_float(t1 & 0xFFFF0000u);
                ax0 += w2 * __uint_as_float(t2 << 16);
                ay0 += w2 * __uint_as_float(t2 & 0xFFFF0000u);
                ax1 += w3 * __uint_as_float(t3 << 16);
                ay1 += w3 * __uint_as_float(t3 & 0xFFFF0000u);
            }
            for (; i < ke; ++i) {
                const int2 ev = buf[i];
                const u32 tv = Tw[(size_t)ev.x * 64 + lane];
                const float w0 = __int_as_float(ev.y);
                ax0 += w0 * __uint_as_float(tv << 16);
                ay0 += w0 * __uint_as_float(tv & 0xFFFF0000u);
            }

            f32x2 r;
            r[0] = ax0 + ax1;
            r[1] = ay0 + ay1;
            __builtin_nontemporal_store(r, (f32x2*)(out + (size_t)v * DIM + 2 * lane));
        }
    } else {
        // slow-correct fallback: filter-scan the coarse window per node
        for (int nt = 0; nt < 16; ++nt) {
            const int tn = (wv << 4) + nt;
            const int v  = v0 + tn;
            if (v >= n) break;
            const int want = hbit | tn;
            float ax = 0.f, ay = 0.f;
            for (int i = s; i < e; ++i) {
                const int2 ev = es1[i];
                if (((ev.x >> 20) & 255) == want) {
                    const u32 tv = Tw[(size_t)(ev.x & 0xFFFFF) * 64 + lane];
                    const float wgt = __int_as_float(ev.y);
                    ax += wgt * __uint_as_float(tv << 16);
                    ay += wgt * __uint_as_float(tv & 0xFFFF0000u);
                }
            }
            f32x2 r; r[0] = ax; r[1] = ay;
            __builtin_nontemporal_store(r, (f32x2*)(out + (size_t)v * DIM + 2 * lane));
        }
    }
}

// ---------------------------------------------------------------------------
extern "C" void kernel_launch(void* const* d_in, const int* in_sizes, int n_in,
                              void* d_out, int out_size, void* d_ws, size_t ws_size,
                              hipStream_t stream)
{
    const float* node_emb = (const float*)d_in[0];
    const float* ew       = (const float*)d_in[1];
    const int*   src      = (const int*)d_in[2];
    const int*   dst      = (const int*)d_in[3];
    const float* W        = (const float*)d_in[4];
    float* out = (float*)d_out;

    const int n = in_sizes[0] / DIM;            // 100000
    const int E = in_sizes[1];                  // 1600000
    const int NBK = (n + BSIZE - 1) >> BSH;     // 391 coarse buckets
    const int nCntBlk = (E + CHUNK - 1) / CHUNK;// 391 L1 blocks
    const int M = NBK * nCntBlk;
    const int nfine = (n + FBS - 1) / FBS;      // 782 aggregate blocks

    // workspace layout (256B-aligned chunks)
    char* ws = (char*)d_ws;
    size_t o = 0;
    u16* Tb = (u16*)(ws + o);  o += (((size_t)n * DIM * sizeof(u16)) + 255) & ~255ULL;
    int* cnt = (int*)(ws + o); o += (((size_t)M * sizeof(int)) + 255) & ~255ULL;
    int* tot = (int*)(ws + o); o += (((size_t)NBK * sizeof(int)) + 255) & ~255ULL;
    int* bucketStart = (int*)(ws + o); o += (((size_t)(NBK + 1) * sizeof(int)) + 255) & ~255ULL;
    int2* es1 = (int2*)(ws + o);

    const int ntiles = (n + 63) >> 6;           // 64 rows per transform block

    // zero tot (tiny, capture-safe — verified passing in r12)
    hipMemsetAsync(tot, 0, (size_t)NBK * sizeof(int), stream);

    // K1: fused L1-count (+rowsum via atomics) + MFMA transform
    k_count_transform<<<nCntBlk + ntiles, 256, 0, stream>>>(
        node_emb, W, Tb, dst, cnt, tot, n, E, nCntBlk, NBK);

    // K2: fused bucket-scan + row-scan (cnt-matrix based, r11 form)
    k_scan_all<<<NBK, 512, 0, stream>>>(tot, bucketStart, cnt, NBK, nCntBlk, E);

    // K3: LDS-staged L1 scatter with coalesced flush (block-exclusive runs)
    k_scatter<<<nCntBlk, 512, 0, stream>>>(src, dst, ew, cnt, bucketStart,
                                           es1, E, nCntBlk, NBK);

    // K5: fused filter + fine-sort + aggregate (512 threads, 8 waves/block)
    gnn_aggregate<<<nfine, 512, 0, stream>>>(Tb, bucketStart, es1, out, n);
}

// Round 14
// 231.774 us; speedup vs baseline: 1.0141x; 1.0027x over previous
//
#include <hip/hip_runtime.h>
#include <cstdint>

typedef unsigned short u16;
typedef unsigned int   u32;

#define DIM     128
#define TPITCH  136          // LDS W row pitch in bf16 (bank-spread)
#define BSH     7            // nodes per bucket = 128 (exact K5 windows)
#define BSIZE   128
#define NBK_MAX 800          // supports n <= 102400 at BSIZE=128
#define CHUNK   4096         // edges per L1 sort block
#define FBS     128          // nodes per aggregate block == BSIZE
#define CAP     2560         // LDS edge capacity (mean 2048, sd ~45, +11 sigma)

__device__ __forceinline__ u16 f2bf(float x) {   // fp32 -> bf16 RTNE
    u32 u = __float_as_uint(x);
    u32 r = u + 0x7FFFu + ((u >> 16) & 1u);
    return (u16)(r >> 16);
}

typedef __attribute__((ext_vector_type(8))) short bfrag;
typedef __attribute__((ext_vector_type(4))) float f32x4;
typedef __attribute__((ext_vector_type(2))) float f32x2;

// ---------------------------------------------------------------------------
// K1 (fat): blocks [0, nCntBlk) do the L1 bucket count (782 buckets); the
// rest compute T(bf16) = A @ W^T with MFMA, restaging the C-tile through LDS
// for coalesced dwordx4 Tb writes. (r11-measured form, bucket width halved.)
// ---------------------------------------------------------------------------
__global__ __launch_bounds__(256) void k_count_transform(
    const float* __restrict__ A, const float* __restrict__ W,
    u16* __restrict__ Tb,
    const int* __restrict__ dst, int* __restrict__ cnt,
    int n, int E, int nCntBlk, int NBK)
{
    __shared__ u16 Wb[DIM * TPITCH];   // 34816 B; count blocks reuse as hist

    if (blockIdx.x < nCntBlk) {
        int* hist = (int*)Wb;          // NBK ints (3.1 KB) fit easily
        for (int i = threadIdx.x; i < NBK; i += 256) hist[i] = 0;
        __syncthreads();
        const int base = blockIdx.x * CHUNK;
        const int end  = min(base + CHUNK, E);
        for (int i = base + threadIdx.x; i < end; i += 256)
            atomicAdd(&hist[dst[i] >> BSH], 1);
        __syncthreads();
        for (int b = threadIdx.x; b < NBK; b += 256)
            cnt[b * nCntBlk + blockIdx.x] = hist[b];
        return;
    }

    // stage W as bf16: Wb[j][k] = bf16(W[j][k]); thread t -> row t>>1, half (t&1)*64
    {
        const int j  = threadIdx.x >> 1;
        const int k0 = (threadIdx.x & 1) << 6;
        const float* wr = W + j * DIM + k0;
        u16* wo = Wb + j * TPITCH + k0;
#pragma unroll
        for (int k = 0; k < 64; k += 4) {
            float4 v = *(const float4*)(wr + k);
            ushort4 h;
            h.x = f2bf(v.x); h.y = f2bf(v.y); h.z = f2bf(v.z); h.w = f2bf(v.w);
            *(ushort4*)(wo + k) = h;
        }
    }
    __syncthreads();

    const int wave = threadIdx.x >> 6;
    const int lane = threadIdx.x & 63;
    const int quad = lane >> 4;
    const int l16  = lane & 15;

    const int r0b = (blockIdx.x - nCntBlk) << 6;          // block's first row
    const int r0  = r0b + (wave << 4);                    // wave's first row
    const bool active = (r0 < n);                         // predicate, no return

    f32x4 acc[8];
#pragma unroll
    for (int c = 0; c < 8; ++c) acc[c] = (f32x4)(0.f);

    if (active) {
        const int ar = min(r0 + l16, n - 1);   // A-frag row (clamped on tail)
        const float* arow = A + (size_t)ar * DIM;
#pragma unroll
        for (int s = 0; s < 4; ++s) {
            const int koff = (s << 5) + (quad << 3);
            const float4 f0 = *(const float4*)(arow + koff);
            const float4 f1 = *(const float4*)(arow + koff + 4);
            bfrag a;
            a[0] = (short)f2bf(f0.x); a[1] = (short)f2bf(f0.y);
            a[2] = (short)f2bf(f0.z); a[3] = (short)f2bf(f0.w);
            a[4] = (short)f2bf(f1.x); a[5] = (short)f2bf(f1.y);
            a[6] = (short)f2bf(f1.z); a[7] = (short)f2bf(f1.w);
#pragma unroll
            for (int c = 0; c < 8; ++c) {
                const int nn = (c << 4) + l16;     // B col; B[k][n] = W[n][k]
                const bfrag b = *(const bfrag*)(Wb + nn * TPITCH + koff);
                acc[c] = __builtin_amdgcn_mfma_f32_16x16x32_bf16(a, b, acc[c], 0, 0, 0);
            }
        }
    }

    __syncthreads();                 // all Wb reads complete; reuse as C-tile

    // restage C: tile[row_local][col], pitch TPITCH (bank-spread)
    if (active) {
        const int rl0 = (wave << 4) + (quad << 2);
#pragma unroll
        for (int r = 0; r < 4; ++r) {
            u16* trow = Wb + (rl0 + r) * TPITCH + l16;
#pragma unroll
            for (int c = 0; c < 8; ++c)
                trow[c << 4] = f2bf(acc[c][r]);
        }
    }
    __syncthreads();

    // coalesced flush: thread t -> row t>>2, 64B chunk t&3 (4 x dwordx4)
    {
        const int rl  = threadIdx.x >> 2;
        const int row = r0b + rl;
        if (row < n) {
            const float4* sp = (const float4*)(Wb + rl * TPITCH + ((threadIdx.x & 3) << 5));
            float4* dp = (float4*)(Tb + (size_t)row * DIM + ((threadIdx.x & 3) << 5));
            dp[0] = sp[0];
            dp[1] = sp[1];
            dp[2] = sp[2];
            dp[3] = sp[3];
        }
    }
}

// ---------------------------------------------------------------------------
// K2a: tot[b] = sum of cnt row b (nCntBlk values)
// ---------------------------------------------------------------------------
__global__ __launch_bounds__(256) void k_rowsum(
    const int* __restrict__ cnt, int* __restrict__ tot, int nCntBlk)
{
    __shared__ int red[256];
    const int t = threadIdx.x;
    const int* row = cnt + blockIdx.x * nCntBlk;
    int s = 0;
    for (int i = t; i < nCntBlk; i += 256) s += row[i];
    red[t] = s; __syncthreads();
    for (int o = 128; o; o >>= 1) {
        if (t < o) red[t] += red[t + o];
        __syncthreads();
    }
    if (t == 0) tot[blockIdx.x] = red[0];
}

// ---------------------------------------------------------------------------
// K2bc (fused): every block recomputes bucketStart = exscan(tot) in LDS
// (chunked, NBK up to 800); block 0 publishes it; each block then scans its
// cnt row (nCntBlk <= 512) offset by its bucket base.
// ---------------------------------------------------------------------------
__global__ __launch_bounds__(512) void k_scan_all(
    const int* __restrict__ tot, int* __restrict__ bucketStart,
    int* __restrict__ cnt, int NBK, int nCntBlk, int E)
{
    __shared__ int sc[512];
    __shared__ int bs;                    // this block's bucket base
    __shared__ int carry;
    const int t = threadIdx.x;
    const int b = blockIdx.x;
    if (t == 0) carry = 0;
    __syncthreads();

    // pass 1: chunked scan of tot[NBK]
    for (int c0 = 0; c0 < NBK; c0 += 512) {
        const int idx = c0 + t;
        const int v = (idx < NBK) ? tot[idx] : 0;
        sc[t] = v; __syncthreads();
        for (int d = 1; d < 512; d <<= 1) {
            int u = (t >= d) ? sc[t - d] : 0;
            __syncthreads();
            sc[t] += u;
            __syncthreads();
        }
        const int excl = carry + sc[t] - v;
        if (idx == b) bs = excl;
        if (b == 0 && idx < NBK) bucketStart[idx] = excl;
        __syncthreads();
        if (t == 0) carry += sc[511];
        __syncthreads();
    }
    if (b == 0 && t == 0) bucketStart[NBK] = E;

    // pass 2: scan cnt row b (nCntBlk <= 512), offset by bs
    int* row = cnt + b * nCntBlk;
    const int rv = (t < nCntBlk) ? row[t] : 0;
    sc[t] = rv; __syncthreads();
    for (int d = 1; d < 512; d <<= 1) {
        int u = (t >= d) ? sc[t - d] : 0;
        __syncthreads();
        sc[t] += u;
        __syncthreads();
    }
    if (t < nCntBlk) row[t] = bs + sc[t] - rv;
}

// ---------------------------------------------------------------------------
// K3: L1 scatter, LDS-staged, block-exclusive deterministic runs from the
// scanned cnt matrix (r11-measured form; NBK now 782 -> chunked scan).
// Payload: x = src | (dst&127)<<20, y = w bits. (avg run 5.2 edges = 42 B)
// ---------------------------------------------------------------------------
__global__ __launch_bounds__(512) void k_scatter(
    const int* __restrict__ src, const int* __restrict__ dst,
    const float* __restrict__ w, const int* __restrict__ cnt,
    const int* __restrict__ bucketStart,
    int2* __restrict__ es1, int E, int nCntBlk, int NBK)
{
    __shared__ int2 buf[CHUNK];          // 32 KB staged payload
    __shared__ u16  bid[CHUNK];          // bucket id per slot (8 KB)
    __shared__ int  gbase[NBK_MAX];      // global run base for this block
    __shared__ int  lbase[NBK_MAX];      // local run base in buf
    __shared__ int  lpos[NBK_MAX];       // running local position
    __shared__ int  sc[512];             // scan scratch
    __shared__ int  carry;

    const int blk  = blockIdx.x;
    const int base = blk * CHUNK;
    const int end  = min(base + CHUNK, E);
    const int len  = end - base;
    const int t    = threadIdx.x;

    if (t == 0) carry = 0;
    __syncthreads();

    // chunked: run length per bucket from cnt matrix -> lbase/lpos via scan
    for (int c0 = 0; c0 < NBK; c0 += 512) {
        const int idx = c0 + t;
        int v = 0;
        if (idx < NBK) {
            const int g = cnt[idx * nCntBlk + blk];
            gbase[idx] = g;
            const int nxt = (blk + 1 < nCntBlk) ? cnt[idx * nCntBlk + blk + 1]
                                                : bucketStart[idx + 1];
            v = nxt - g;
        }
        sc[t] = v;
        __syncthreads();
        for (int d = 1; d < 512; d <<= 1) {
            int u = (t >= d) ? sc[t - d] : 0;
            __syncthreads();
            sc[t] += u;
            __syncthreads();
        }
        const int ex = carry + sc[t] - v;
        if (idx < NBK) {
            lbase[idx] = ex;
            lpos[idx]  = ex;
        }
        __syncthreads();
        if (t == 0) carry += sc[511];
        __syncthreads();
    }

    // scatter into LDS (scattered 8B writes stay on-chip)
    for (int i = base + t; i < end; i += 512) {
        const int d   = dst[i];
        const int bkt = d >> BSH;
        const int p   = atomicAdd(&lpos[bkt], 1);
        buf[p] = make_int2(src[i] | ((d & (BSIZE - 1)) << 20),
                           __float_as_int(w[i]));
        bid[p] = (u16)bkt;
    }
    __syncthreads();

    // coalesced flush: consecutive i -> consecutive global addresses per run
    for (int i = t; i < len; i += 512) {
        const int bkt = bid[i];
        es1[gbase[bkt] + (i - lbase[bkt])] = buf[i];
    }
}

// ---------------------------------------------------------------------------
// K5 (fused fine-sort + aggregate): one block per 128-node bucket, EXACT
// window (no filter, no read amplification). Phase A: count -> scan ->
// scatter ~2048 edges into a 20 KB LDS CSR. Phase B: measured-best unroll-8
// per-node loop. 512 threads (8 waves), wave owns 16 nodes.
// ---------------------------------------------------------------------------
__global__ __launch_bounds__(512) void gnn_aggregate(
    const u16* __restrict__ Tb, const int* __restrict__ bucketStart,
    const int2* __restrict__ es1, float* __restrict__ out, int n)
{
    __shared__ int2 buf[CAP];           // 20 KB sorted edges
    __shared__ int  cnt[FBS];
    __shared__ int  loff[FBS + 1];
    __shared__ int  cur[FBS];
    __shared__ int  sc[FBS];

    const int f    = blockIdx.x;
    const int s    = bucketStart[f], e = bucketStart[f + 1];
    const int len  = e - s;
    const int v0   = f << BSH;          // first node id of this block
    const int t    = threadIdx.x;
    const int lane = t & 63;
    const int wv   = t >> 6;            // 0..7
    const u32* Tw  = (const u32*)Tb;

    if (t < FBS) cnt[t] = 0;
    __syncthreads();
    for (int i = s + t; i < e; i += 512)
        atomicAdd(&cnt[(es1[i].x >> 20) & 127], 1);
    __syncthreads();

    int myc = 0;
    if (t < FBS) { myc = cnt[t]; sc[t] = myc; }
    __syncthreads();
    for (int d = 1; d < FBS; d <<= 1) {
        int u = 0;
        if (t < FBS && t >= d) u = sc[t - d];
        __syncthreads();
        if (t < FBS) sc[t] += u;
        __syncthreads();
    }
    if (t < FBS) {
        const int ex = sc[t] - myc;
        loff[t] = ex; cur[t] = ex;
        if (t == FBS - 1) loff[FBS] = sc[t];   // == len
    }
    __syncthreads();

    if (len <= CAP) {
        for (int i = s + t; i < e; i += 512) {
            const int2 ev = es1[i];
            const int p = atomicAdd(&cur[(ev.x >> 20) & 127], 1);
            buf[p] = make_int2(ev.x & 0xFFFFF, ev.y);
        }
        __syncthreads();

        // phase B: wave wv owns local nodes [wv*16, wv*16+16)
        for (int nt = 0; nt < 16; ++nt) {
            const int tn = (wv << 4) + nt;
            const int v  = v0 + tn;
            if (v >= n) break;                    // wave-uniform
            const int kb = loff[tn], ke = loff[tn + 1];
            float ax0 = 0.f, ay0 = 0.f, ax1 = 0.f, ay1 = 0.f;

            int i = kb;
            for (; i + 7 < ke; i += 8) {
                const int2 e0 = buf[i],     e1 = buf[i + 1], e2 = buf[i + 2], e3 = buf[i + 3];
                const int2 e4 = buf[i + 4], e5 = buf[i + 5], e6 = buf[i + 6], e7 = buf[i + 7];
                const u32 t0 = Tw[(size_t)e0.x * 64 + lane];
                const u32 t1 = Tw[(size_t)e1.x * 64 + lane];
                const u32 t2 = Tw[(size_t)e2.x * 64 + lane];
                const u32 t3 = Tw[(size_t)e3.x * 64 + lane];
                const u32 t4 = Tw[(size_t)e4.x * 64 + lane];
                const u32 t5 = Tw[(size_t)e5.x * 64 + lane];
                const u32 t6 = Tw[(size_t)e6.x * 64 + lane];
                const u32 t7 = Tw[(size_t)e7.x * 64 + lane];
                const float w0 = __int_as_float(e0.y), w1 = __int_as_float(e1.y);
                const float w2 = __int_as_float(e2.y), w3 = __int_as_float(e3.y);
                const float w4 = __int_as_float(e4.y), w5 = __int_as_float(e5.y);
                const float w6 = __int_as_float(e6.y), w7 = __int_as_float(e7.y);
                ax0 += w0 * __uint_as_float(t0 << 16);
                ay0 += w0 * __uint_as_float(t0 & 0xFFFF0000u);
                ax1 += w1 * __uint_as_float(t1 << 16);
                ay1 += w1 * __uint_as_float(t1 & 0xFFFF0000u);
                ax0 += w2 * __uint_as_float(t2 << 16);
                ay0 += w2 * __uint_as_float(t2 & 0xFFFF0000u);
                ax1 += w3 * __uint_as_float(t3 << 16);
                ay1 += w3 * __uint_as_float(t3 & 0xFFFF0000u);
                ax0 += w4 * __uint_as_float(t4 << 16);
                ay0 += w4 * __uint_as_float(t4 & 0xFFFF0000u);
                ax1 += w5 * __uint_as_float(t5 << 16);
                ay1 += w5 * __uint_as_float(t5 & 0xFFFF0000u);
                ax0 += w6 * __uint_as_float(t6 << 16);
                ay0 += w6 * __uint_as_float(t6 & 0xFFFF0000u);
                ax1 += w7 * __uint_as_float(t7 << 16);
                ay1 += w7 * __uint_as_float(t7 & 0xFFFF0000u);
            }
            for (; i + 3 < ke; i += 4) {
                const int2 e0 = buf[i], e1 = buf[i + 1], e2 = buf[i + 2], e3 = buf[i + 3];
                const u32 t0 = Tw[(size_t)e0.x * 64 + lane];
                const u32 t1 = Tw[(size_t)e1.x * 64 + lane];
                const u32 t2 = Tw[(size_t)e2.x * 64 + lane];
                const u32 t3 = Tw[(size_t)e3.x * 64 + lane];
                const float w0 = __int_as_float(e0.y), w1 = __int_as_float(e1.y);
                const float w2 = __int_as_float(e2.y), w3 = __int_as_float(e3.y);
                ax0 += w0 * __uint_as_float(t0 << 16);
                ay0 += w0 * __uint_as_float(t0 & 0xFFFF0000u);
                ax1 += w1 * __uint_as_float(t1 << 16);
                ay1 += w1 * __uint_as_float(t1 & 0xFFFF0000u);
                ax0 += w2 * __uint_as_float(t2 << 16);
                ay0 += w2 * __uint_as_float(t2 & 0xFFFF0000u);
                ax1 += w3 * __uint_as_float(t3 << 16);
                ay1 += w3 * __uint_as_float(t3 & 0xFFFF0000u);
            }
            for (; i < ke; ++i) {
                const int2 ev = buf[i];
                const u32 tv = Tw[(size_t)ev.x * 64 + lane];
                const float w0 = __int_as_float(ev.y);
                ax0 += w0 * __uint_as_float(tv << 16);
                ay0 += w0 * __uint_as_float(tv & 0xFFFF0000u);
            }

            f32x2 r;
            r[0] = ax0 + ax1;
            r[1] = ay0 + ay1;
            __builtin_nontemporal_store(r, (f32x2*)(out + (size_t)v * DIM + 2 * lane));
        }
    } else {
        // slow-correct fallback: filter-scan the window per node (never hit)
        for (int nt = 0; nt < 16; ++nt) {
            const int tn = (wv << 4) + nt;
            const int v  = v0 + tn;
            if (v >= n) break;
            float ax = 0.f, ay = 0.f;
            for (int i = s; i < e; ++i) {
                const int2 ev = es1[i];
                if (((ev.x >> 20) & 127) == tn) {
                    const u32 tv = Tw[(size_t)(ev.x & 0xFFFFF) * 64 + lane];
                    const float wgt = __int_as_float(ev.y);
                    ax += wgt * __uint_as_float(tv << 16);
                    ay += wgt * __uint_as_float(tv & 0xFFFF0000u);
                }
            }
            f32x2 r; r[0] = ax; r[1] = ay;
            __builtin_nontemporal_store(r, (f32x2*)(out + (size_t)v * DIM + 2 * lane));
        }
    }
}

// ---------------------------------------------------------------------------
extern "C" void kernel_launch(void* const* d_in, const int* in_sizes, int n_in,
                              void* d_out, int out_size, void* d_ws, size_t ws_size,
                              hipStream_t stream)
{
    const float* node_emb = (const float*)d_in[0];
    const float* ew       = (const float*)d_in[1];
    const int*   src      = (const int*)d_in[2];
    const int*   dst      = (const int*)d_in[3];
    const float* W        = (const float*)d_in[4];
    float* out = (float*)d_out;

    const int n = in_sizes[0] / DIM;            // 100000
    const int E = in_sizes[1];                  // 1600000
    const int NBK = (n + BSIZE - 1) >> BSH;     // 782 buckets (128 nodes each)
    const int nCntBlk = (E + CHUNK - 1) / CHUNK;// 391 L1 blocks
    const int M = NBK * nCntBlk;

    // workspace layout (256B-aligned chunks)
    char* ws = (char*)d_ws;
    size_t o = 0;
    u16* Tb = (u16*)(ws + o);  o += (((size_t)n * DIM * sizeof(u16)) + 255) & ~255ULL;
    int* cnt = (int*)(ws + o); o += (((size_t)M * sizeof(int)) + 255) & ~255ULL;
    int* tot = (int*)(ws + o); o += (((size_t)NBK * sizeof(int)) + 255) & ~255ULL;
    int* bucketStart = (int*)(ws + o); o += (((size_t)(NBK + 1) * sizeof(int)) + 255) & ~255ULL;
    int2* es1 = (int2*)(ws + o);

    const int ntiles = (n + 63) >> 6;           // 64 rows per transform block

    // K1: fused L1-count + MFMA transform
    k_count_transform<<<nCntBlk + ntiles, 256, 0, stream>>>(
        node_emb, W, Tb, dst, cnt, n, E, nCntBlk, NBK);

    // K2: row sums, then fused bucket-scan + row-scan
    k_rowsum<<<NBK, 256, 0, stream>>>(cnt, tot, nCntBlk);
    k_scan_all<<<NBK, 512, 0, stream>>>(tot, bucketStart, cnt, NBK, nCntBlk, E);

    // K3: LDS-staged L1 scatter, block-exclusive runs (128-node buckets)
    k_scatter<<<nCntBlk, 512, 0, stream>>>(src, dst, ew, cnt, bucketStart,
                                           es1, E, nCntBlk, NBK);

    // K5: fused fine-sort + aggregate, exact windows (no filter)
    gnn_aggregate<<<NBK, 512, 0, stream>>>(Tb, bucketStart, es1, out, n);
}

// Round 15
// 214.507 us; speedup vs baseline: 1.0958x; 1.0805x over previous
//
#include <hip/hip_runtime.h>
#include <cstdint>

typedef unsigned short u16;
typedef unsigned int   u32;

#define DIM     128
#define TPITCH  136          // LDS W row pitch in bf16 (bank-spread)
#define BSH     8            // nodes per coarse bucket = 256
#define BSIZE   256
#define NBK_MAX 512          // supports n <= 131072 at BSIZE=256
#define CHUNK   4096         // edges per L1 sort block
#define FBS     128          // nodes per fused-aggregate block (half bucket)
#define CAP     2560         // LDS edge capacity (mean 2048, sd ~45, +11 sigma)

__device__ __forceinline__ u16 f2bf(float x) {   // fp32 -> bf16 RTNE
    u32 u = __float_as_uint(x);
    u32 r = u + 0x7FFFu + ((u >> 16) & 1u);
    return (u16)(r >> 16);
}

typedef __attribute__((ext_vector_type(8))) short bfrag;
typedef __attribute__((ext_vector_type(4))) float f32x4;
typedef __attribute__((ext_vector_type(2))) float f32x2;

// ---------------------------------------------------------------------------
// K1: L1 bucket count only (391 blocks). The MFMA transform moved into the
// scatter dispatch (K3fat) so it runs OFF the critical path, concurrent with
// the scatter. Count -> scan -> scatter is the only serial chain.
// ---------------------------------------------------------------------------
__global__ __launch_bounds__(256) void k_count(
    const int* __restrict__ dst, int* __restrict__ cnt,
    int E, int nCntBlk, int NBK)
{
    __shared__ int hist[NBK_MAX];
    for (int i = threadIdx.x; i < NBK; i += 256) hist[i] = 0;
    __syncthreads();
    const int base = blockIdx.x * CHUNK;
    const int end  = min(base + CHUNK, E);
    for (int i = base + threadIdx.x; i < end; i += 256)
        atomicAdd(&hist[dst[i] >> BSH], 1);
    __syncthreads();
    for (int b = threadIdx.x; b < NBK; b += 256)
        cnt[b * nCntBlk + blockIdx.x] = hist[b];
}

// ---------------------------------------------------------------------------
// K2a: tot[b] = sum of cnt row b (nCntBlk values)
// ---------------------------------------------------------------------------
__global__ __launch_bounds__(256) void k_rowsum(
    const int* __restrict__ cnt, int* __restrict__ tot, int nCntBlk)
{
    __shared__ int red[256];
    const int t = threadIdx.x;
    const int* row = cnt + blockIdx.x * nCntBlk;
    int s = 0;
    for (int i = t; i < nCntBlk; i += 256) s += row[i];
    red[t] = s; __syncthreads();
    for (int o = 128; o; o >>= 1) {
        if (t < o) red[t] += red[t + o];
        __syncthreads();
    }
    if (t == 0) tot[blockIdx.x] = red[0];
}

// ---------------------------------------------------------------------------
// K2bc (fused): every block recomputes bucketStart = exscan(tot) in LDS;
// block 0 publishes it; each block then scans its cnt row offset by its base.
// ---------------------------------------------------------------------------
__global__ __launch_bounds__(512) void k_scan_all(
    const int* __restrict__ tot, int* __restrict__ bucketStart,
    int* __restrict__ cnt, int NBK, int nCntBlk, int E)
{
    __shared__ int sc[512];
    __shared__ int bs;                    // this block's bucket base
    const int t = threadIdx.x;
    const int b = blockIdx.x;

    // pass 1: scan tot
    const int v = (t < NBK) ? tot[t] : 0;
    sc[t] = v; __syncthreads();
    for (int d = 1; d < 512; d <<= 1) {
        int u = (t >= d) ? sc[t - d] : 0;
        __syncthreads();
        sc[t] += u;
        __syncthreads();
    }
    if (t == b) bs = sc[t] - v;           // exclusive prefix at b (b < 512)
    if (b == 0) {
        if (t < NBK) bucketStart[t] = sc[t] - v;
        if (t == 0)  bucketStart[NBK] = E;
    }
    __syncthreads();                      // bs visible; sc reusable

    // pass 2: scan cnt row b, offset by bs
    int* row = cnt + b * nCntBlk;
    const int rv = (t < nCntBlk) ? row[t] : 0;
    sc[t] = rv; __syncthreads();
    for (int d = 1; d < 512; d <<= 1) {
        int u = (t >= d) ? sc[t - d] : 0;
        __syncthreads();
        sc[t] += u;
        __syncthreads();
    }
    if (t < nCntBlk) row[t] = bs + sc[t] - rv;
}

// ---------------------------------------------------------------------------
// K3fat: blocks [0, nCntBlk) = LDS-staged scatter (r11-measured form);
// blocks [nCntBlk, ...) = MFMA transform at 128 rows/block (512 thr, 8
// waves), restaging C through LDS for coalesced dwordx4 Tb writes.
// The two roles share one 48 KB LDS union; scatter blocks dispatch first
// (critical path), transform fills the machine alongside.
// ---------------------------------------------------------------------------
__global__ __launch_bounds__(512) void k_scatter_transform(
    const int* __restrict__ src, const int* __restrict__ dst,
    const float* __restrict__ w, const int* __restrict__ cnt,
    const int* __restrict__ bucketStart, int2* __restrict__ es1,
    const float* __restrict__ A, const float* __restrict__ W,
    u16* __restrict__ Tb,
    int n, int E, int nCntBlk, int NBK)
{
    __shared__ __align__(16) char smem[49152];   // 48 KB union

    const int t = threadIdx.x;

    if (blockIdx.x < nCntBlk) {
        // ----- scatter role (r11 form) -----
        int2* buf   = (int2*)smem;                 // 32768 B
        u16*  bid   = (u16*)(smem + 32768);        //  8192 B
        int*  gbase = (int*)(smem + 40960);        //  2048 B
        int*  lbase = (int*)(smem + 43008);        //  2048 B
        int*  lpos  = (int*)(smem + 45056);        //  2048 B
        int*  sc    = (int*)(smem + 47104);        //  2048 B

        const int blk  = blockIdx.x;
        const int base = blk * CHUNK;
        const int end  = min(base + CHUNK, E);
        const int len  = end - base;

        int mylen = 0;
        if (t < NBK) {
            const int g = cnt[t * nCntBlk + blk];
            gbase[t] = g;
            const int nxt = (blk + 1 < nCntBlk) ? cnt[t * nCntBlk + blk + 1]
                                                : bucketStart[t + 1];
            mylen = nxt - g;
        }
        sc[t] = (t < NBK) ? mylen : 0;
        __syncthreads();
        for (int d = 1; d < 512; d <<= 1) {
            int v = (t >= d) ? sc[t - d] : 0;
            __syncthreads();
            sc[t] += v;
            __syncthreads();
        }
        if (t < NBK) {
            const int ex = sc[t] - mylen;    // exclusive scan -> local base
            lbase[t] = ex;
            lpos[t]  = ex;
        }
        __syncthreads();

        for (int i = base + t; i < end; i += 512) {
            const int d   = dst[i];
            const int bkt = d >> BSH;
            const int p   = atomicAdd(&lpos[bkt], 1);
            buf[p] = make_int2(src[i] | ((d & (BSIZE - 1)) << 20),
                               __float_as_int(w[i]));
            bid[p] = (u16)bkt;
        }
        __syncthreads();

        for (int i = t; i < len; i += 512) {
            const int bkt = bid[i];
            es1[gbase[bkt] + (i - lbase[bkt])] = buf[i];
        }
        return;
    }

    // ----- transform role: 128 rows/block, 8 waves -----
    u16* Wb = (u16*)smem;                          // 128 * 136 * 2 = 34816 B

    // stage W as bf16: thread t -> row t>>2, quarter (t&3)*32
    {
        const int j  = t >> 2;
        const int k0 = (t & 3) << 5;
        const float* wr = W + j * DIM + k0;
        u16* wo = Wb + j * TPITCH + k0;
#pragma unroll
        for (int k = 0; k < 32; k += 4) {
            float4 v = *(const float4*)(wr + k);
            ushort4 h;
            h.x = f2bf(v.x); h.y = f2bf(v.y); h.z = f2bf(v.z); h.w = f2bf(v.w);
            *(ushort4*)(wo + k) = h;
        }
    }
    __syncthreads();

    const int wave = t >> 6;                       // 0..7
    const int lane = t & 63;
    const int quad = lane >> 4;
    const int l16  = lane & 15;

    const int r0b = (blockIdx.x - nCntBlk) << 7;   // block's first row (128/blk)
    const int r0  = r0b + (wave << 4);             // wave's first row
    const bool active = (r0 < n);                  // predicate, no return

    f32x4 acc[8];
#pragma unroll
    for (int c = 0; c < 8; ++c) acc[c] = (f32x4)(0.f);

    if (active) {
        const int ar = min(r0 + l16, n - 1);       // A-frag row (clamped)
        const float* arow = A + (size_t)ar * DIM;
#pragma unroll
        for (int s = 0; s < 4; ++s) {
            const int koff = (s << 5) + (quad << 3);
            const float4 f0 = *(const float4*)(arow + koff);
            const float4 f1 = *(const float4*)(arow + koff + 4);
            bfrag a;
            a[0] = (short)f2bf(f0.x); a[1] = (short)f2bf(f0.y);
            a[2] = (short)f2bf(f0.z); a[3] = (short)f2bf(f0.w);
            a[4] = (short)f2bf(f1.x); a[5] = (short)f2bf(f1.y);
            a[6] = (short)f2bf(f1.z); a[7] = (short)f2bf(f1.w);
#pragma unroll
            for (int c = 0; c < 8; ++c) {
                const int nn = (c << 4) + l16;     // B col; B[k][n] = W[n][k]
                const bfrag b = *(const bfrag*)(Wb + nn * TPITCH + koff);
                acc[c] = __builtin_amdgcn_mfma_f32_16x16x32_bf16(a, b, acc[c], 0, 0, 0);
            }
        }
    }

    __syncthreads();                 // all Wb reads complete; reuse as C-tile

    // restage C: tile[row_local][col], pitch TPITCH (bank-spread)
    if (active) {
        const int rl0 = (wave << 4) + (quad << 2);
#pragma unroll
        for (int r = 0; r < 4; ++r) {
            u16* trow = Wb + (rl0 + r) * TPITCH + l16;
#pragma unroll
            for (int c = 0; c < 8; ++c)
                trow[c << 4] = f2bf(acc[c][r]);
        }
    }
    __syncthreads();

    // coalesced flush: thread t -> row t>>2, 64B chunk t&3 (4 x dwordx4)
    {
        const int rl  = t >> 2;                    // 0..127
        const int row = r0b + rl;
        if (row < n) {
            const float4* sp = (const float4*)(Wb + rl * TPITCH + ((t & 3) << 5));
            float4* dp = (float4*)(Tb + (size_t)row * DIM + ((t & 3) << 5));
            dp[0] = sp[0];
            dp[1] = sp[1];
            dp[2] = sp[2];
            dp[3] = sp[3];
        }
    }
}

// ---------------------------------------------------------------------------
// K5 (fused fine-sort + aggregate): one block per 128-node half-bucket,
// 512 threads (8 waves). Filter on dlocal high bit, 20 KB LDS CSR sort,
// then the measured-best unroll-8 per-node loop. (r11 form, unchanged.)
// ---------------------------------------------------------------------------
__global__ __launch_bounds__(512) void gnn_aggregate(
    const u16* __restrict__ Tb, const int* __restrict__ bucketStart,
    const int2* __restrict__ es1, float* __restrict__ out, int n)
{
    __shared__ int2 buf[CAP];           // 20 KB sorted edges
    __shared__ int  cnt[FBS];
    __shared__ int  loff[FBS + 1];
    __shared__ int  cur[FBS];
    __shared__ int  sc[FBS];

    const int f    = blockIdx.x;
    const int c    = f >> 1;            // parent coarse bucket
    const int hbit = (f & 1) << 7;      // half selector on dlocal bit 7
    const int s    = bucketStart[c], e = bucketStart[c + 1];
    const int v0   = f << 7;            // first node id of this block
    const int t    = threadIdx.x;
    const int lane = t & 63;
    const int wv   = t >> 6;            // 0..7
    const u32* Tw  = (const u32*)Tb;

    if (t < FBS) cnt[t] = 0;
    __syncthreads();
    for (int i = s + t; i < e; i += 512) {
        const int d8 = (es1[i].x >> 20) & 255;
        if ((d8 & 128) == hbit) atomicAdd(&cnt[d8 & 127], 1);
    }
    __syncthreads();

    int myc = 0;
    if (t < FBS) { myc = cnt[t]; sc[t] = myc; }
    __syncthreads();
    for (int d = 1; d < FBS; d <<= 1) {
        int u = 0;
        if (t < FBS && t >= d) u = sc[t - d];
        __syncthreads();
        if (t < FBS) sc[t] += u;
        __syncthreads();
    }
    if (t < FBS) {
        const int ex = sc[t] - myc;
        loff[t] = ex; cur[t] = ex;
        if (t == FBS - 1) loff[FBS] = sc[t];   // == kept edge count
    }
    __syncthreads();
    const int kept = loff[FBS];

    if (kept <= CAP) {
        for (int i = s + t; i < e; i += 512) {
            const int2 ev = es1[i];
            const int d8 = (ev.x >> 20) & 255;
            if ((d8 & 128) == hbit) {
                const int p = atomicAdd(&cur[d8 & 127], 1);
                buf[p] = make_int2(ev.x & 0xFFFFF, ev.y);
            }
        }
        __syncthreads();

        // phase B: wave wv owns local nodes [wv*16, wv*16+16)
        for (int nt = 0; nt < 16; ++nt) {
            const int tn = (wv << 4) + nt;
            const int v  = v0 + tn;
            if (v >= n) break;                    // wave-uniform
            const int kb = loff[tn], ke = loff[tn + 1];
            float ax0 = 0.f, ay0 = 0.f, ax1 = 0.f, ay1 = 0.f;

            int i = kb;
            for (; i + 7 < ke; i += 8) {
                const int2 e0 = buf[i],     e1 = buf[i + 1], e2 = buf[i + 2], e3 = buf[i + 3];
                const int2 e4 = buf[i + 4], e5 = buf[i + 5], e6 = buf[i + 6], e7 = buf[i + 7];
                const u32 t0 = Tw[(size_t)e0.x * 64 + lane];
                const u32 t1 = Tw[(size_t)e1.x * 64 + lane];
                const u32 t2 = Tw[(size_t)e2.x * 64 + lane];
                const u32 t3 = Tw[(size_t)e3.x * 64 + lane];
                const u32 t4 = Tw[(size_t)e4.x * 64 + lane];
                const u32 t5 = Tw[(size_t)e5.x * 64 + lane];
                const u32 t6 = Tw[(size_t)e6.x * 64 + lane];
                const u32 t7 = Tw[(size_t)e7.x * 64 + lane];
                const float w0 = __int_as_float(e0.y), w1 = __int_as_float(e1.y);
                const float w2 = __int_as_float(e2.y), w3 = __int_as_float(e3.y);
                const float w4 = __int_as_float(e4.y), w5 = __int_as_float(e5.y);
                const float w6 = __int_as_float(e6.y), w7 = __int_as_float(e7.y);
                ax0 += w0 * __uint_as_float(t0 << 16);
                ay0 += w0 * __uint_as_float(t0 & 0xFFFF0000u);
                ax1 += w1 * __uint_as_float(t1 << 16);
                ay1 += w1 * __uint_as_float(t1 & 0xFFFF0000u);
                ax0 += w2 * __uint_as_float(t2 << 16);
                ay0 += w2 * __uint_as_float(t2 & 0xFFFF0000u);
                ax1 += w3 * __uint_as_float(t3 << 16);
                ay1 += w3 * __uint_as_float(t3 & 0xFFFF0000u);
                ax0 += w4 * __uint_as_float(t4 << 16);
                ay0 += w4 * __uint_as_float(t4 & 0xFFFF0000u);
                ax1 += w5 * __uint_as_float(t5 << 16);
                ay1 += w5 * __uint_as_float(t5 & 0xFFFF0000u);
                ax0 += w6 * __uint_as_float(t6 << 16);
                ay0 += w6 * __uint_as_float(t6 & 0xFFFF0000u);
                ax1 += w7 * __uint_as_float(t7 << 16);
                ay1 += w7 * __uint_as_float(t7 & 0xFFFF0000u);
            }
            for (; i + 3 < ke; i += 4) {
                const int2 e0 = buf[i], e1 = buf[i + 1], e2 = buf[i + 2], e3 = buf[i + 3];
                const u32 t0 = Tw[(size_t)e0.x * 64 + lane];
                const u32 t1 = Tw[(size_t)e1.x * 64 + lane];
                const u32 t2 = Tw[(size_t)e2.x * 64 + lane];
                const u32 t3 = Tw[(size_t)e3.x * 64 + lane];
                const float w0 = __int_as_float(e0.y), w1 = __int_as_float(e1.y);
                const float w2 = __int_as_float(e2.y), w3 = __int_as_float(e3.y);
                ax0 += w0 * __uint_as_float(t0 << 16);
                ay0 += w0 * __uint_as_float(t0 & 0xFFFF0000u);
                ax1 += w1 * __uint_as_float(t1 << 16);
                ay1 += w1 * __uint_as_float(t1 & 0xFFFF0000u);
                ax0 += w2 * __uint_as_float(t2 << 16);
                ay0 += w2 * __uint_as_float(t2 & 0xFFFF0000u);
                ax1 += w3 * __uint_as_float(t3 << 16);
                ay1 += w3 * __uint_as_float(t3 & 0xFFFF0000u);
            }
            for (; i < ke; ++i) {
                const int2 ev = buf[i];
                const u32 tv = Tw[(size_t)ev.x * 64 + lane];
                const float w0 = __int_as_float(ev.y);
                ax0 += w0 * __uint_as_float(tv << 16);
                ay0 += w0 * __uint_as_float(tv & 0xFFFF0000u);
            }

            f32x2 r;
            r[0] = ax0 + ax1;
            r[1] = ay0 + ay1;
            __builtin_nontemporal_store(r, (f32x2*)(out + (size_t)v * DIM + 2 * lane));
        }
    } else {
        // slow-correct fallback: filter-scan the coarse window per node
        for (int nt = 0; nt < 16; ++nt) {
            const int tn = (wv << 4) + nt;
            const int v  = v0 + tn;
            if (v >= n) break;
            const int want = hbit | tn;
            float ax = 0.f, ay = 0.f;
            for (int i = s; i < e; ++i) {
                const int2 ev = es1[i];
                if (((ev.x >> 20) & 255) == want) {
                    const u32 tv = Tw[(size_t)(ev.x & 0xFFFFF) * 64 + lane];
                    const float wgt = __int_as_float(ev.y);
                    ax += wgt * __uint_as_float(tv << 16);
                    ay += wgt * __uint_as_float(tv & 0xFFFF0000u);
                }
            }
            f32x2 r; r[0] = ax; r[1] = ay;
            __builtin_nontemporal_store(r, (f32x2*)(out + (size_t)v * DIM + 2 * lane));
        }
    }
}

// ---------------------------------------------------------------------------
extern "C" void kernel_launch(void* const* d_in, const int* in_sizes, int n_in,
                              void* d_out, int out_size, void* d_ws, size_t ws_size,
                              hipStream_t stream)
{
    const float* node_emb = (const float*)d_in[0];
    const float* ew       = (const float*)d_in[1];
    const int*   src      = (const int*)d_in[2];
    const int*   dst      = (const int*)d_in[3];
    const float* W        = (const float*)d_in[4];
    float* out = (float*)d_out;

    const int n = in_sizes[0] / DIM;            // 100000
    const int E = in_sizes[1];                  // 1600000
    const int NBK = (n + BSIZE - 1) >> BSH;     // 391 coarse buckets
    const int nCntBlk = (E + CHUNK - 1) / CHUNK;// 391 L1 blocks
    const int M = NBK * nCntBlk;
    const int nfine = (n + FBS - 1) / FBS;      // 782 aggregate blocks

    // workspace layout (256B-aligned chunks)
    char* ws = (char*)d_ws;
    size_t o = 0;
    u16* Tb = (u16*)(ws + o);  o += (((size_t)n * DIM * sizeof(u16)) + 255) & ~255ULL;
    int* cnt = (int*)(ws + o); o += (((size_t)M * sizeof(int)) + 255) & ~255ULL;
    int* tot = (int*)(ws + o); o += (((size_t)NBK * sizeof(int)) + 255) & ~255ULL;
    int* bucketStart = (int*)(ws + o); o += (((size_t)(NBK + 1) * sizeof(int)) + 255) & ~255ULL;
    int2* es1 = (int2*)(ws + o);

    const int ntiles = (n + 127) >> 7;          // 128 rows per transform block

    // K1: count only (critical path starts here; transform deferred)
    k_count<<<nCntBlk, 256, 0, stream>>>(dst, cnt, E, nCntBlk, NBK);

    // K2: row sums, then fused bucket-scan + row-scan
    k_rowsum<<<NBK, 256, 0, stream>>>(cnt, tot, nCntBlk);
    k_scan_all<<<NBK, 512, 0, stream>>>(tot, bucketStart, cnt, NBK, nCntBlk, E);

    // K3fat: scatter (critical path) + MFMA transform (off-path) concurrent
    k_scatter_transform<<<nCntBlk + ntiles, 512, 0, stream>>>(
        src, dst, ew, cnt, bucketStart, es1, node_emb, W, Tb,
        n, E, nCntBlk, NBK);

    // K5: fused filter + fine-sort + aggregate (512 threads, 8 waves/block)
    gnn_aggregate<<<nfine, 512, 0, stream>>>(Tb, bucketStart, es1, out, n);
}